// Round 2
// baseline (252.649 us; speedup 1.0000x reference)
//
#include <hip/hip_runtime.h>
#include <math.h>

#define EMBED   256
#define NCAM    6
#define NLVL    4
#define NPTS    13
#define NGRP    8
#define NANCH   900
#define NTERM   (NCAM*NLVL*NPTS)   /* 312 */
#define KOUT    (NTERM*NGRP)       /* 2496 */
#define TOTHW   14960

// ---------------------------------------------------------------------------
// Generic tiled f32 GEMM:  C[m][n] = dot(A0[m]+A1[m], B[n]) + bias[n]
// A: M x K row-major (optionally sum of two tensors), B: N x K row-major.
// BM=BN=64, BK=32, 256 threads, 4x4 accumulators per thread.
// ---------------------------------------------------------------------------
__global__ __launch_bounds__(256)
void gemm_bias_f32(const float* __restrict__ A0, const float* __restrict__ A1,
                   const float* __restrict__ B,  const float* __restrict__ bias,
                   float* __restrict__ Cout, int M, int N, int K)
{
    const int BM = 64, BN = 64, BK = 32;
    __shared__ float As[32][64 + 1];
    __shared__ float Bs[32][64 + 1];

    const int bm = blockIdx.y * BM;
    const int bn = blockIdx.x * BN;
    const int tid = threadIdx.x;
    const int tx = tid & 15;       // n direction
    const int ty = tid >> 4;       // m direction

    float acc[4][4] = {{0.f}};

    for (int k0 = 0; k0 < K; k0 += BK) {
        // ---- load A tile (BM x BK) ----
        #pragma unroll
        for (int i = 0; i < 2; ++i) {
            int lin = (tid + i * 256) * 4;       // element in tile, row-major
            int r = lin >> 5;                    // /BK
            int cc = lin & 31;                   // %BK
            int gm = bm + r;
            float4 v = make_float4(0.f, 0.f, 0.f, 0.f);
            if (gm < M) {
                v = *reinterpret_cast<const float4*>(A0 + (size_t)gm * K + k0 + cc);
                if (A1) {
                    float4 v1 = *reinterpret_cast<const float4*>(A1 + (size_t)gm * K + k0 + cc);
                    v.x += v1.x; v.y += v1.y; v.z += v1.z; v.w += v1.w;
                }
            }
            As[cc + 0][r] = v.x; As[cc + 1][r] = v.y;
            As[cc + 2][r] = v.z; As[cc + 3][r] = v.w;
        }
        // ---- load B tile (BN x BK) ----
        #pragma unroll
        for (int i = 0; i < 2; ++i) {
            int lin = (tid + i * 256) * 4;
            int r = lin >> 5;
            int cc = lin & 31;
            int gn = bn + r;
            float4 v = make_float4(0.f, 0.f, 0.f, 0.f);
            if (gn < N) {
                v = *reinterpret_cast<const float4*>(B + (size_t)gn * K + k0 + cc);
            }
            Bs[cc + 0][r] = v.x; Bs[cc + 1][r] = v.y;
            Bs[cc + 2][r] = v.z; Bs[cc + 3][r] = v.w;
        }
        __syncthreads();

        #pragma unroll
        for (int k = 0; k < BK; ++k) {
            float a[4], b[4];
            #pragma unroll
            for (int i = 0; i < 4; ++i) a[i] = As[k][ty * 4 + i];
            #pragma unroll
            for (int j = 0; j < 4; ++j) b[j] = Bs[k][tx * 4 + j];
            #pragma unroll
            for (int i = 0; i < 4; ++i)
                #pragma unroll
                for (int j = 0; j < 4; ++j)
                    acc[i][j] = fmaf(a[i], b[j], acc[i][j]);
        }
        __syncthreads();
    }

    #pragma unroll
    for (int i = 0; i < 4; ++i) {
        int m = bm + ty * 4 + i;
        if (m >= M) break;
        #pragma unroll
        for (int j = 0; j < 4; ++j) {
            int n = bn + tx * 4 + j;
            if (n < N) Cout[(size_t)m * N + n] = acc[i][j] + (bias ? bias[n] : 0.f);
        }
    }
}

// ---------------------------------------------------------------------------
// Per-anchor: softmax over 312 terms per group, project 13 pts through 6 cams,
// bilinear-gather 256-ch features at 4 levels, aggregate with weights.
// One block per anchor, 256 threads (one per channel).
// ---------------------------------------------------------------------------
__global__ __launch_bounds__(256)
void sample_agg(const float* __restrict__ feat,        // (NCAM, TOTHW, 256)
                const float* __restrict__ key_points,  // (900, 13, 3)
                const float* __restrict__ lidar2img,   // (6, 4, 4)
                const float* __restrict__ image_wh,    // (6, 2)
                const float* __restrict__ logits,      // (900, 2496) raw
                float* __restrict__ outacc)            // (900, 256)
{
    __shared__ alignas(16) float wl[KOUT];             // [m][g], softmaxed in place
    __shared__ alignas(16) int   cidx[NTERM][4];
    __shared__ alignas(16) float cwgt[NTERM][4];
    __shared__ int tmap[NTERM];
    __shared__ int ncomp;

    const int a   = blockIdx.x;
    const int tid = threadIdx.x;

    if (tid == 0) ncomp = 0;

    // ---- 1. load logits to LDS (float4, coalesced) ----
    {
        const float4* src = reinterpret_cast<const float4*>(logits + (size_t)a * KOUT);
        float4* dst = reinterpret_cast<float4*>(wl);
        for (int i = tid; i < KOUT / 4; i += 256) dst[i] = src[i];
    }
    __syncthreads();

    // ---- 2. softmax over m (312) per group g; 32 lanes per group ----
    {
        int g = tid >> 5;        // 0..7
        int j = tid & 31;
        float mx = -1e30f;
        for (int m = j; m < NTERM; m += 32) mx = fmaxf(mx, wl[m * NGRP + g]);
        #pragma unroll
        for (int s = 16; s > 0; s >>= 1) mx = fmaxf(mx, __shfl_xor(mx, s, 32));
        float sum = 0.f;
        for (int m = j; m < NTERM; m += 32) {
            float e = __expf(wl[m * NGRP + g] - mx);
            wl[m * NGRP + g] = e;
            sum += e;
        }
        #pragma unroll
        for (int s = 16; s > 0; s >>= 1) sum += __shfl_xor(sum, s, 32);
        float inv = 1.f / sum;
        for (int m = j; m < NTERM; m += 32) wl[m * NGRP + g] *= inv;
    }

    // ---- 3. geometry: per-term bilinear corner indices+weights, compacted ----
    for (int t = tid; t < NTERM; t += 256) {
        int cam = t / (NLVL * NPTS);
        int rem = t - cam * (NLVL * NPTS);
        int lvl = rem / NPTS;
        int p   = rem - lvl * NPTS;

        const float* kp = key_points + ((size_t)a * NPTS + p) * 3;
        float px = kp[0], py = kp[1], pz = kp[2];
        const float* M4 = lidar2img + cam * 16;
        float X = M4[0] * px + M4[1] * py + M4[2]  * pz + M4[3];
        float Y = M4[4] * px + M4[5] * py + M4[6]  * pz + M4[7];
        float Z = M4[8] * px + M4[9] * py + M4[10] * pz + M4[11];
        float zc = fmaxf(Z, 1e-5f);
        float u = (X / zc) / image_wh[cam * 2 + 0];
        float v = (Y / zc) / image_wh[cam * 2 + 1];

        int H = 64 >> lvl, W = 176 >> lvl;
        int st = (lvl == 0) ? 0 : (lvl == 1) ? 11264 : (lvl == 2) ? 14080 : 14784;

        float x = u * (float)W - 0.5f;
        float y = v * (float)H - 0.5f;
        float x0f = floorf(x), y0f = floorf(y);
        float wx1 = x - x0f, wy1 = y - y0f;
        float wx0 = 1.f - wx1, wy0 = 1.f - wy1;
        int x0 = (int)x0f, y0 = (int)y0f;
        int x1 = x0 + 1,   y1 = y0 + 1;

        bool vx0 = (x0 >= 0) & (x0 < W), vx1 = (x1 >= 0) & (x1 < W);
        bool vy0 = (y0 >= 0) & (y0 < H), vy1 = (y1 >= 0) & (y1 < H);
        int cx0 = min(max(x0, 0), W - 1), cx1 = min(max(x1, 0), W - 1);
        int cy0 = min(max(y0, 0), H - 1), cy1 = min(max(y1, 0), H - 1);

        float w00 = wx0 * wy0 * ((vx0 & vy0) ? 1.f : 0.f);
        float w10 = wx1 * wy0 * ((vx1 & vy0) ? 1.f : 0.f);
        float w01 = wx0 * wy1 * ((vx0 & vy1) ? 1.f : 0.f);
        float w11 = wx1 * wy1 * ((vx1 & vy1) ? 1.f : 0.f);

        if ((w00 != 0.f) | (w10 != 0.f) | (w01 != 0.f) | (w11 != 0.f)) {
            int slot = atomicAdd(&ncomp, 1);
            int base = cam * TOTHW + st;
            cidx[slot][0] = base + cy0 * W + cx0;
            cidx[slot][1] = base + cy0 * W + cx1;
            cidx[slot][2] = base + cy1 * W + cx0;
            cidx[slot][3] = base + cy1 * W + cx1;
            cwgt[slot][0] = w00;
            cwgt[slot][1] = w10;
            cwgt[slot][2] = w01;
            cwgt[slot][3] = w11;
            tmap[slot] = t;
        }
    }
    __syncthreads();

    // ---- 4. gather + aggregate: one channel per thread ----
    const int c = tid;
    const int g = c >> 5;                 // C/G = 32
    const int nt = ncomp;
    float acc = 0.f;
    const float* fbase = feat + c;

    #pragma unroll 4
    for (int s = 0; s < nt; ++s) {
        int4   I  = *reinterpret_cast<const int4*>(&cidx[s][0]);
        float4 Wt = *reinterpret_cast<const float4*>(&cwgt[s][0]);
        float  gw = wl[tmap[s] * NGRP + g];
        float v0 = fbase[(size_t)I.x * EMBED];
        float v1 = fbase[(size_t)I.y * EMBED];
        float v2 = fbase[(size_t)I.z * EMBED];
        float v3 = fbase[(size_t)I.w * EMBED];
        float sv = v0 * Wt.x + v1 * Wt.y + v2 * Wt.z + v3 * Wt.w;
        acc = fmaf(sv, gw, acc);
    }
    outacc[(size_t)a * EMBED + c] = acc;
}

// ---------------------------------------------------------------------------
extern "C" void kernel_launch(void* const* d_in, const int* in_sizes, int n_in,
                              void* d_out, int out_size, void* d_ws, size_t ws_size,
                              hipStream_t stream)
{
    const float* feat   = (const float*)d_in[0];
    const float* kp     = (const float*)d_in[1];
    const float* l2i    = (const float*)d_in[2];
    const float* iwh    = (const float*)d_in[3];
    const float* inst   = (const float*)d_in[4];
    const float* anch   = (const float*)d_in[5];
    const float* wfc    = (const float*)d_in[6];
    const float* bfc    = (const float*)d_in[7];
    const float* wproj  = (const float*)d_in[8];
    const float* bproj  = (const float*)d_in[9];
    float* out = (float*)d_out;

    float* logits = (float*)d_ws;                             // 900*2496 f32
    float* outacc = logits + (size_t)NANCH * KOUT;            // 900*256  f32

    // K1: logits = (inst + anch) @ wfc^T + bfc     (M=900, N=2496, K=256)
    {
        dim3 grid(KOUT / 64, (NANCH + 63) / 64);              // 39 x 15
        gemm_bias_f32<<<grid, 256, 0, stream>>>(inst, anch, wfc, bfc,
                                                logits, NANCH, KOUT, EMBED);
    }

    // K2: softmax + project + bilinear sample + aggregate
    sample_agg<<<dim3(NANCH), 256, 0, stream>>>(feat, kp, l2i, iwh, logits, outacc);

    // K3: out = outacc @ wproj^T + bproj           (M=900, N=256, K=256)
    {
        dim3 grid(EMBED / 64, (NANCH + 63) / 64);             // 4 x 15
        gemm_bias_f32<<<grid, 256, 0, stream>>>(outacc, nullptr, wproj, bproj,
                                                out, NANCH, EMBED, EMBED);
    }
}

// Round 4
// 235.592 us; speedup vs baseline: 1.0724x; 1.0724x over previous
//
#include <hip/hip_runtime.h>
#include <math.h>

#define EMBED   256
#define NCAM    6
#define NLVL    4
#define NPTS    13
#define NGRP    8
#define NANCH   900
#define NTERM   (NCAM*NLVL*NPTS)   /* 312 */
#define KOUT    (NTERM*NGRP)       /* 2496 */
#define TOTHW   14960
#define SPLIT   4
#define TPS     (NTERM/SPLIT)      /* 78 terms per split block */

// ---------------------------------------------------------------------------
// Tiled f32 GEMM:  C[m][n] = dot(A0[m]+A1[m], B[n]) + bias[n]
// A: M x K row-major (optionally sum of two tensors), B: N x K row-major.
// BM=BN=64, BK=32, 256 threads, 4x4 accumulators; LDS padded to 68 floats/row
// so fragment reads are 16B-aligned ds_read_b128.
// ---------------------------------------------------------------------------
__global__ __launch_bounds__(256)
void gemm_bias_f32(const float* __restrict__ A0, const float* __restrict__ A1,
                   const float* __restrict__ B,  const float* __restrict__ bias,
                   float* __restrict__ Cout, int M, int N, int K)
{
    const int BK = 32;
    __shared__ alignas(16) float As[32][68];   // [k][m], row stride 272B = 17*16B
    __shared__ alignas(16) float Bs[32][68];   // [k][n]

    const int bm = blockIdx.y * 64;
    const int bn = blockIdx.x * 64;
    const int tid = threadIdx.x;
    const int tx = tid & 15;       // n direction
    const int ty = tid >> 4;       // m direction

    float acc[4][4] = {{0.f}};

    for (int k0 = 0; k0 < K; k0 += BK) {
        #pragma unroll
        for (int i = 0; i < 2; ++i) {
            int lin = (tid + i * 256) * 4;       // element in 64x32 tile, row-major
            int r = lin >> 5;                    // row (m or n)
            int cc = lin & 31;                   // k
            int gm = bm + r;
            float4 v = make_float4(0.f, 0.f, 0.f, 0.f);
            if (gm < M) {
                v = *reinterpret_cast<const float4*>(A0 + (size_t)gm * K + k0 + cc);
                if (A1) {
                    float4 v1 = *reinterpret_cast<const float4*>(A1 + (size_t)gm * K + k0 + cc);
                    v.x += v1.x; v.y += v1.y; v.z += v1.z; v.w += v1.w;
                }
            }
            As[cc + 0][r] = v.x; As[cc + 1][r] = v.y;
            As[cc + 2][r] = v.z; As[cc + 3][r] = v.w;

            int gn = bn + r;
            float4 w = make_float4(0.f, 0.f, 0.f, 0.f);
            if (gn < N) {
                w = *reinterpret_cast<const float4*>(B + (size_t)gn * K + k0 + cc);
            }
            Bs[cc + 0][r] = w.x; Bs[cc + 1][r] = w.y;
            Bs[cc + 2][r] = w.z; Bs[cc + 3][r] = w.w;
        }
        __syncthreads();

        #pragma unroll
        for (int k = 0; k < BK; ++k) {
            float4 a4 = *reinterpret_cast<const float4*>(&As[k][ty * 4]);
            float4 b4 = *reinterpret_cast<const float4*>(&Bs[k][tx * 4]);
            float a[4] = {a4.x, a4.y, a4.z, a4.w};
            float b[4] = {b4.x, b4.y, b4.z, b4.w};
            #pragma unroll
            for (int i = 0; i < 4; ++i)
                #pragma unroll
                for (int j = 0; j < 4; ++j)
                    acc[i][j] = fmaf(a[i], b[j], acc[i][j]);
        }
        __syncthreads();
    }

    #pragma unroll
    for (int i = 0; i < 4; ++i) {
        int m = bm + ty * 4 + i;
        if (m >= M) break;
        #pragma unroll
        for (int j = 0; j < 4; ++j) {
            int n = bn + tx * 4 + j;
            if (n < N) Cout[(size_t)m * N + n] = acc[i][j] + (bias ? bias[n] : 0.f);
        }
    }
}

// ---------------------------------------------------------------------------
// Softmax over 312 terms per (anchor, group); also zero-inits outacc.
// One block per anchor, 256 threads; 32 lanes per group.
// ---------------------------------------------------------------------------
__global__ __launch_bounds__(256)
void softmax_k(const float* __restrict__ logits,   // (900, 2496)
               float* __restrict__ wsm,            // (900, 2496) out
               float* __restrict__ outacc)         // (900, 256)  zeroed
{
    __shared__ alignas(16) float wl[KOUT];
    const int a   = blockIdx.x;
    const int tid = threadIdx.x;

    {
        const float4* src = reinterpret_cast<const float4*>(logits + (size_t)a * KOUT);
        float4* dst = reinterpret_cast<float4*>(wl);
        for (int i = tid; i < KOUT / 4; i += 256) dst[i] = src[i];
    }
    __syncthreads();

    int g = tid >> 5;        // 0..7
    int j = tid & 31;
    float mx = -1e30f;
    for (int m = j; m < NTERM; m += 32) mx = fmaxf(mx, wl[m * NGRP + g]);
    #pragma unroll
    for (int s = 16; s > 0; s >>= 1) mx = fmaxf(mx, __shfl_xor(mx, s, 32));
    float sum = 0.f;
    for (int m = j; m < NTERM; m += 32) {
        float e = __expf(wl[m * NGRP + g] - mx);
        wl[m * NGRP + g] = e;
        sum += e;
    }
    #pragma unroll
    for (int s = 16; s > 0; s >>= 1) sum += __shfl_xor(sum, s, 32);
    float inv = 1.f / sum;
    for (int m = j; m < NTERM; m += 32) wl[m * NGRP + g] *= inv;
    __syncthreads();

    {
        const float4* src = reinterpret_cast<const float4*>(wl);
        float4* dst = reinterpret_cast<float4*>(wsm + (size_t)a * KOUT);
        for (int i = tid; i < KOUT / 4; i += 256) dst[i] = src[i];
    }
    outacc[(size_t)a * EMBED + tid] = 0.f;
}

// ---------------------------------------------------------------------------
// Split sample+aggregate: block = (anchor, split); each handles 78 terms.
// 256 threads = one per channel; accumulate into outacc via atomicAdd.
// ---------------------------------------------------------------------------
__global__ __launch_bounds__(256)
void sample_agg_split(const float* __restrict__ feat,        // (NCAM, TOTHW, 256)
                      const float* __restrict__ key_points,  // (900, 13, 3)
                      const float* __restrict__ lidar2img,   // (6, 4, 4)
                      const float* __restrict__ image_wh,    // (6, 2)
                      const float* __restrict__ wsm,         // (900, 2496) softmaxed
                      float* __restrict__ outacc)            // (900, 256)
{
    __shared__ alignas(16) float wl[TPS * NGRP];   // 624 floats, this split's chunk
    __shared__ alignas(16) int   cidx[TPS][4];     // *EMBED pre-multiplied
    __shared__ alignas(16) float cwgt[TPS][4];
    __shared__ int tmap[TPS];
    __shared__ int ncomp;

    const int bid = blockIdx.x;
    const int a   = bid >> 2;          // / SPLIT
    const int sp  = bid & (SPLIT - 1);
    const int t0  = sp * TPS;
    const int tid = threadIdx.x;

    if (tid == 0) ncomp = 0;
    // ---- load this split's softmaxed weights chunk ----
    {
        const float4* src = reinterpret_cast<const float4*>(wsm + (size_t)a * KOUT + t0 * NGRP);
        float4* dst = reinterpret_cast<float4*>(wl);
        if (tid < TPS * NGRP / 4) dst[tid] = src[tid];   // 156 float4
    }
    __syncthreads();

    // ---- geometry for local terms, compacted ----
    if (tid < TPS) {
        int t = t0 + tid;
        int cam = t / (NLVL * NPTS);
        int rem = t - cam * (NLVL * NPTS);
        int lvl = rem / NPTS;
        int p   = rem - lvl * NPTS;

        const float* kp = key_points + ((size_t)a * NPTS + p) * 3;
        float px = kp[0], py = kp[1], pz = kp[2];
        const float* M4 = lidar2img + cam * 16;
        float X = M4[0] * px + M4[1] * py + M4[2]  * pz + M4[3];
        float Y = M4[4] * px + M4[5] * py + M4[6]  * pz + M4[7];
        float Z = M4[8] * px + M4[9] * py + M4[10] * pz + M4[11];
        float zc = fmaxf(Z, 1e-5f);
        float u = (X / zc) / image_wh[cam * 2 + 0];
        float v = (Y / zc) / image_wh[cam * 2 + 1];

        int H = 64 >> lvl, W = 176 >> lvl;
        int st = (lvl == 0) ? 0 : (lvl == 1) ? 11264 : (lvl == 2) ? 14080 : 14784;

        float x = u * (float)W - 0.5f;
        float y = v * (float)H - 0.5f;
        float x0f = floorf(x), y0f = floorf(y);
        float wx1 = x - x0f, wy1 = y - y0f;
        float wx0 = 1.f - wx1, wy0 = 1.f - wy1;
        int x0 = (int)x0f, y0 = (int)y0f;
        int x1 = x0 + 1,   y1 = y0 + 1;

        bool vx0 = (x0 >= 0) & (x0 < W), vx1 = (x1 >= 0) & (x1 < W);
        bool vy0 = (y0 >= 0) & (y0 < H), vy1 = (y1 >= 0) & (y1 < H);
        int cx0 = min(max(x0, 0), W - 1), cx1 = min(max(x1, 0), W - 1);
        int cy0 = min(max(y0, 0), H - 1), cy1 = min(max(y1, 0), H - 1);

        float w00 = wx0 * wy0 * ((vx0 & vy0) ? 1.f : 0.f);
        float w10 = wx1 * wy0 * ((vx1 & vy0) ? 1.f : 0.f);
        float w01 = wx0 * wy1 * ((vx0 & vy1) ? 1.f : 0.f);
        float w11 = wx1 * wy1 * ((vx1 & vy1) ? 1.f : 0.f);

        if ((w00 != 0.f) | (w10 != 0.f) | (w01 != 0.f) | (w11 != 0.f)) {
            int slot = atomicAdd(&ncomp, 1);
            int base = cam * TOTHW + st;
            cidx[slot][0] = (base + cy0 * W + cx0) * EMBED;
            cidx[slot][1] = (base + cy0 * W + cx1) * EMBED;
            cidx[slot][2] = (base + cy1 * W + cx0) * EMBED;
            cidx[slot][3] = (base + cy1 * W + cx1) * EMBED;
            cwgt[slot][0] = w00;
            cwgt[slot][1] = w10;
            cwgt[slot][2] = w01;
            cwgt[slot][3] = w11;
            tmap[slot] = tid;               // local term index
        }
    }
    __syncthreads();

    // ---- gather + aggregate: one channel per thread ----
    const int c = tid;
    const int g = c >> 5;                 // C/G = 32
    const int nt = ncomp;
    float acc = 0.f;
    const float* fbase = feat + c;

    #pragma unroll 4
    for (int s = 0; s < nt; ++s) {
        int4   I  = *reinterpret_cast<const int4*>(&cidx[s][0]);
        float4 Wt = *reinterpret_cast<const float4*>(&cwgt[s][0]);
        float  gw = wl[tmap[s] * NGRP + g];
        float v0 = fbase[I.x];
        float v1 = fbase[I.y];
        float v2 = fbase[I.z];
        float v3 = fbase[I.w];
        float sv = v0 * Wt.x + v1 * Wt.y + v2 * Wt.z + v3 * Wt.w;
        acc = fmaf(sv, gw, acc);
    }
    atomicAdd(&outacc[(size_t)a * EMBED + c], acc);
}

// ---------------------------------------------------------------------------
extern "C" void kernel_launch(void* const* d_in, const int* in_sizes, int n_in,
                              void* d_out, int out_size, void* d_ws, size_t ws_size,
                              hipStream_t stream)
{
    const float* feat   = (const float*)d_in[0];
    const float* kp     = (const float*)d_in[1];
    const float* l2i    = (const float*)d_in[2];
    const float* iwh    = (const float*)d_in[3];
    const float* inst   = (const float*)d_in[4];
    const float* anch   = (const float*)d_in[5];
    const float* wfc    = (const float*)d_in[6];
    const float* bfc    = (const float*)d_in[7];
    const float* wproj  = (const float*)d_in[8];
    const float* bproj  = (const float*)d_in[9];
    float* out = (float*)d_out;

    float* logits = (float*)d_ws;                             // 900*2496 f32
    float* wsm    = logits + (size_t)NANCH * KOUT;            // 900*2496 f32
    float* outacc = wsm    + (size_t)NANCH * KOUT;            // 900*256  f32

    // K1: logits = (inst + anch) @ wfc^T + bfc     (M=900, N=2496, K=256)
    {
        dim3 grid(KOUT / 64, (NANCH + 63) / 64);              // 39 x 15
        gemm_bias_f32<<<grid, 256, 0, stream>>>(inst, anch, wfc, bfc,
                                                logits, NANCH, KOUT, EMBED);
    }

    // K1.5: softmax (+ zero outacc)
    softmax_k<<<dim3(NANCH), 256, 0, stream>>>(logits, wsm, outacc);

    // K2: split sample + aggregate (atomic accumulate)
    sample_agg_split<<<dim3(NANCH * SPLIT), 256, 0, stream>>>(feat, kp, l2i, iwh,
                                                              wsm, outacc);

    // K3: out = outacc @ wproj^T + bproj           (M=900, N=256, K=256)
    {
        dim3 grid(EMBED / 64, (NANCH + 63) / 64);             // 4 x 15
        gemm_bias_f32<<<grid, 256, 0, stream>>>(outacc, nullptr, wproj, bproj,
                                                out, NANCH, EMBED, EMBED);
    }
}

// Round 7
// 234.058 us; speedup vs baseline: 1.0794x; 1.0066x over previous
//
#include <hip/hip_runtime.h>
#include <math.h>

#define EMBED   256
#define NCAM    6
#define NLVL    4
#define NPTS    13
#define NGRP    8
#define NANCH   900
#define NTERM   (NCAM*NLVL*NPTS)   /* 312 */
#define KOUT    (NTERM*NGRP)       /* 2496 */
#define TOTHW   14960
#define SPLIT   4
#define TPS     (NTERM/SPLIT)      /* 78 terms per split block */
#define WSTR    9                  /* LDS stride for [m][g] weights: odd => conflict-free */

// ---------------------------------------------------------------------------
// Tiled f32 GEMM:  C[m][n] = dot(A0[m]+A1[m], B[n]) + bias[n]
// BM=BN=64, BK=32, 256 threads, 4x4 accumulators; LDS padded to 68 floats/row
// so fragment reads are 16B-aligned ds_read_b128.
// ---------------------------------------------------------------------------
__global__ __launch_bounds__(256)
void gemm_bias_f32(const float* __restrict__ A0, const float* __restrict__ A1,
                   const float* __restrict__ B,  const float* __restrict__ bias,
                   float* __restrict__ Cout, int M, int N, int K)
{
    const int BK = 32;
    __shared__ alignas(16) float As[32][68];
    __shared__ alignas(16) float Bs[32][68];

    const int bm = blockIdx.y * 64;
    const int bn = blockIdx.x * 64;
    const int tid = threadIdx.x;
    const int tx = tid & 15;
    const int ty = tid >> 4;

    float acc[4][4] = {{0.f}};

    for (int k0 = 0; k0 < K; k0 += BK) {
        #pragma unroll
        for (int i = 0; i < 2; ++i) {
            int lin = (tid + i * 256) * 4;
            int r = lin >> 5;
            int cc = lin & 31;
            int gm = bm + r;
            float4 v = make_float4(0.f, 0.f, 0.f, 0.f);
            if (gm < M) {
                v = *reinterpret_cast<const float4*>(A0 + (size_t)gm * K + k0 + cc);
                if (A1) {
                    float4 v1 = *reinterpret_cast<const float4*>(A1 + (size_t)gm * K + k0 + cc);
                    v.x += v1.x; v.y += v1.y; v.z += v1.z; v.w += v1.w;
                }
            }
            As[cc + 0][r] = v.x; As[cc + 1][r] = v.y;
            As[cc + 2][r] = v.z; As[cc + 3][r] = v.w;

            int gn = bn + r;
            float4 w = make_float4(0.f, 0.f, 0.f, 0.f);
            if (gn < N) {
                w = *reinterpret_cast<const float4*>(B + (size_t)gn * K + k0 + cc);
            }
            Bs[cc + 0][r] = w.x; Bs[cc + 1][r] = w.y;
            Bs[cc + 2][r] = w.z; Bs[cc + 3][r] = w.w;
        }
        __syncthreads();

        #pragma unroll
        for (int k = 0; k < BK; ++k) {
            float4 a4 = *reinterpret_cast<const float4*>(&As[k][ty * 4]);
            float4 b4 = *reinterpret_cast<const float4*>(&Bs[k][tx * 4]);
            float a[4] = {a4.x, a4.y, a4.z, a4.w};
            float b[4] = {b4.x, b4.y, b4.z, b4.w};
            #pragma unroll
            for (int i = 0; i < 4; ++i)
                #pragma unroll
                for (int j = 0; j < 4; ++j)
                    acc[i][j] = fmaf(a[i], b[j], acc[i][j]);
        }
        __syncthreads();
    }

    #pragma unroll
    for (int i = 0; i < 4; ++i) {
        int m = bm + ty * 4 + i;
        if (m >= M) break;
        #pragma unroll
        for (int j = 0; j < 4; ++j) {
            int n = bn + tx * 4 + j;
            if (n < N) Cout[(size_t)m * N + n] = acc[i][j] + (bias ? bias[n] : 0.f);
        }
    }
}

// ---------------------------------------------------------------------------
// K3 variant: A = sum of 4 partial buffers (outpart[0..3]).
// ---------------------------------------------------------------------------
__global__ __launch_bounds__(256)
void gemm_bias_sum4_f32(const float* __restrict__ Ap,   // 4 x (M x K) stacked
                        const float* __restrict__ B, const float* __restrict__ bias,
                        float* __restrict__ Cout, int M, int N, int K)
{
    const int BK = 32;
    __shared__ alignas(16) float As[32][68];
    __shared__ alignas(16) float Bs[32][68];

    const int bm = blockIdx.y * 64;
    const int bn = blockIdx.x * 64;
    const int tid = threadIdx.x;
    const int tx = tid & 15;
    const int ty = tid >> 4;
    const size_t pstride = (size_t)M * K;

    float acc[4][4] = {{0.f}};

    for (int k0 = 0; k0 < K; k0 += BK) {
        #pragma unroll
        for (int i = 0; i < 2; ++i) {
            int lin = (tid + i * 256) * 4;
            int r = lin >> 5;
            int cc = lin & 31;
            int gm = bm + r;
            float4 v = make_float4(0.f, 0.f, 0.f, 0.f);
            if (gm < M) {
                const float* p = Ap + (size_t)gm * K + k0 + cc;
                float4 v0 = *reinterpret_cast<const float4*>(p);
                float4 v1 = *reinterpret_cast<const float4*>(p + pstride);
                float4 v2 = *reinterpret_cast<const float4*>(p + 2 * pstride);
                float4 v3 = *reinterpret_cast<const float4*>(p + 3 * pstride);
                v.x = v0.x + v1.x + v2.x + v3.x;
                v.y = v0.y + v1.y + v2.y + v3.y;
                v.z = v0.z + v1.z + v2.z + v3.z;
                v.w = v0.w + v1.w + v2.w + v3.w;
            }
            As[cc + 0][r] = v.x; As[cc + 1][r] = v.y;
            As[cc + 2][r] = v.z; As[cc + 3][r] = v.w;

            int gn = bn + r;
            float4 w = make_float4(0.f, 0.f, 0.f, 0.f);
            if (gn < N) {
                w = *reinterpret_cast<const float4*>(B + (size_t)gn * K + k0 + cc);
            }
            Bs[cc + 0][r] = w.x; Bs[cc + 1][r] = w.y;
            Bs[cc + 2][r] = w.z; Bs[cc + 3][r] = w.w;
        }
        __syncthreads();

        #pragma unroll
        for (int k = 0; k < BK; ++k) {
            float4 a4 = *reinterpret_cast<const float4*>(&As[k][ty * 4]);
            float4 b4 = *reinterpret_cast<const float4*>(&Bs[k][tx * 4]);
            float a[4] = {a4.x, a4.y, a4.z, a4.w};
            float b[4] = {b4.x, b4.y, b4.z, b4.w};
            #pragma unroll
            for (int i = 0; i < 4; ++i)
                #pragma unroll
                for (int j = 0; j < 4; ++j)
                    acc[i][j] = fmaf(a[i], b[j], acc[i][j]);
        }
        __syncthreads();
    }

    #pragma unroll
    for (int i = 0; i < 4; ++i) {
        int m = bm + ty * 4 + i;
        if (m >= M) break;
        #pragma unroll
        for (int j = 0; j < 4; ++j) {
            int n = bn + tx * 4 + j;
            if (n < N) Cout[(size_t)m * N + n] = acc[i][j] + (bias ? bias[n] : 0.f);
        }
    }
}

// ---------------------------------------------------------------------------
// Fused split kernel: block = (anchor, split). Loads the anchor's full 2496
// logits, softmaxes in LDS (stride-9 layout: conflict-free), computes geometry
// for its 78 terms (compacted), gathers + aggregates, stores partial sums.
// ---------------------------------------------------------------------------
__global__ __launch_bounds__(256)
void sample_agg_fused(const float* __restrict__ feat,        // (NCAM, TOTHW, 256)
                      const float* __restrict__ key_points,  // (900, 13, 3)
                      const float* __restrict__ lidar2img,   // (6, 4, 4)
                      const float* __restrict__ image_wh,    // (6, 2)
                      const float* __restrict__ logits,      // (900, 2496)
                      float* __restrict__ outpart)           // (4, 900, 256)
{
    __shared__ float wl[NTERM * WSTR];             // 312*9 floats, softmaxed in place
    __shared__ alignas(16) int   cidx[TPS][4];     // *EMBED pre-multiplied
    __shared__ alignas(16) float cwgt[TPS][4];
    __shared__ int tmap[TPS];
    __shared__ int ncomp;

    const int bid = blockIdx.x;
    const int a   = bid >> 2;          // / SPLIT
    const int sp  = bid & (SPLIT - 1);
    const int t0  = sp * TPS;
    const int tid = threadIdx.x;

    if (tid == 0) ncomp = 0;

    // ---- 1. load all logits for this anchor into stride-9 LDS ----
    {
        const float4* src = reinterpret_cast<const float4*>(logits + (size_t)a * KOUT);
        for (int i = tid; i < KOUT / 4; i += 256) {
            float4 v = src[i];
            int e = i * 4;                   // element = m*8+g
            float vv[4] = {v.x, v.y, v.z, v.w};
            #pragma unroll
            for (int q = 0; q < 4; ++q) {
                int m = (e + q) >> 3, g = (e + q) & 7;
                wl[m * WSTR + g] = vv[q];
            }
        }
    }
    __syncthreads();

    // ---- 2. softmax over m (312) per group g; 32 lanes per group ----
    {
        int g = tid >> 5;
        int j = tid & 31;
        float mx = -1e30f;
        for (int m = j; m < NTERM; m += 32) mx = fmaxf(mx, wl[m * WSTR + g]);
        #pragma unroll
        for (int s = 16; s > 0; s >>= 1) mx = fmaxf(mx, __shfl_xor(mx, s, 32));
        float sum = 0.f;
        for (int m = j; m < NTERM; m += 32) {
            float e = __expf(wl[m * WSTR + g] - mx);
            wl[m * WSTR + g] = e;
            sum += e;
        }
        #pragma unroll
        for (int s = 16; s > 0; s >>= 1) sum += __shfl_xor(sum, s, 32);
        float inv = 1.f / sum;
        for (int m = j; m < NTERM; m += 32) wl[m * WSTR + g] *= inv;
    }

    // ---- 3. geometry for this split's terms, compacted ----
    if (tid < TPS) {
        int t = t0 + tid;
        int cam = t / (NLVL * NPTS);
        int rem = t - cam * (NLVL * NPTS);
        int lvl = rem / NPTS;
        int p   = rem - lvl * NPTS;

        const float* kp = key_points + ((size_t)a * NPTS + p) * 3;
        float px = kp[0], py = kp[1], pz = kp[2];
        const float* M4 = lidar2img + cam * 16;
        float X = M4[0] * px + M4[1] * py + M4[2]  * pz + M4[3];
        float Y = M4[4] * px + M4[5] * py + M4[6]  * pz + M4[7];
        float Z = M4[8] * px + M4[9] * py + M4[10] * pz + M4[11];
        float zc = fmaxf(Z, 1e-5f);
        float u = (X / zc) / image_wh[cam * 2 + 0];
        float v = (Y / zc) / image_wh[cam * 2 + 1];

        int H = 64 >> lvl, W = 176 >> lvl;
        int st = (lvl == 0) ? 0 : (lvl == 1) ? 11264 : (lvl == 2) ? 14080 : 14784;

        float x = u * (float)W - 0.5f;
        float y = v * (float)H - 0.5f;
        float x0f = floorf(x), y0f = floorf(y);
        float wx1 = x - x0f, wy1 = y - y0f;
        float wx0 = 1.f - wx1, wy0 = 1.f - wy1;
        int x0 = (int)x0f, y0 = (int)y0f;
        int x1 = x0 + 1,   y1 = y0 + 1;

        bool vx0 = (x0 >= 0) & (x0 < W), vx1 = (x1 >= 0) & (x1 < W);
        bool vy0 = (y0 >= 0) & (y0 < H), vy1 = (y1 >= 0) & (y1 < H);
        int cx0 = min(max(x0, 0), W - 1), cx1 = min(max(x1, 0), W - 1);
        int cy0 = min(max(y0, 0), H - 1), cy1 = min(max(y1, 0), H - 1);

        float w00 = wx0 * wy0 * ((vx0 & vy0) ? 1.f : 0.f);
        float w10 = wx1 * wy0 * ((vx1 & vy0) ? 1.f : 0.f);
        float w01 = wx0 * wy1 * ((vx0 & vy1) ? 1.f : 0.f);
        float w11 = wx1 * wy1 * ((vx1 & vy1) ? 1.f : 0.f);

        if ((w00 != 0.f) | (w10 != 0.f) | (w01 != 0.f) | (w11 != 0.f)) {
            int slot = atomicAdd(&ncomp, 1);
            int base = cam * TOTHW + st;
            cidx[slot][0] = (base + cy0 * W + cx0) * EMBED;
            cidx[slot][1] = (base + cy0 * W + cx1) * EMBED;
            cidx[slot][2] = (base + cy1 * W + cx0) * EMBED;
            cidx[slot][3] = (base + cy1 * W + cx1) * EMBED;
            cwgt[slot][0] = w00;
            cwgt[slot][1] = w10;
            cwgt[slot][2] = w01;
            cwgt[slot][3] = w11;
            tmap[slot] = tid;               // local term index
        }
    }
    __syncthreads();

    // ---- 4. gather + aggregate: one channel per thread ----
    const int c = tid;
    const int g = c >> 5;
    const int nt = ncomp;
    float acc = 0.f;
    const float* fbase = feat + c;

    #pragma unroll 4
    for (int s = 0; s < nt; ++s) {
        int4   I  = *reinterpret_cast<const int4*>(&cidx[s][0]);
        float4 Wt = *reinterpret_cast<const float4*>(&cwgt[s][0]);
        float  gw = wl[(t0 + tmap[s]) * WSTR + g];
        float v0 = fbase[I.x];
        float v1 = fbase[I.y];
        float v2 = fbase[I.z];
        float v3 = fbase[I.w];
        float sv = v0 * Wt.x + v1 * Wt.y + v2 * Wt.z + v3 * Wt.w;
        acc = fmaf(sv, gw, acc);
    }
    outpart[((size_t)sp * NANCH + a) * EMBED + c] = acc;
}

// ---------------------------------------------------------------------------
extern "C" void kernel_launch(void* const* d_in, const int* in_sizes, int n_in,
                              void* d_out, int out_size, void* d_ws, size_t ws_size,
                              hipStream_t stream)
{
    const float* feat   = (const float*)d_in[0];
    const float* kp     = (const float*)d_in[1];
    const float* l2i    = (const float*)d_in[2];
    const float* iwh    = (const float*)d_in[3];
    const float* inst   = (const float*)d_in[4];
    const float* anch   = (const float*)d_in[5];
    const float* wfc    = (const float*)d_in[6];
    const float* bfc    = (const float*)d_in[7];
    const float* wproj  = (const float*)d_in[8];
    const float* bproj  = (const float*)d_in[9];
    float* out = (float*)d_out;

    float* logits  = (float*)d_ws;                            // 900*2496 f32
    float* outpart = logits + (size_t)NANCH * KOUT;           // 4*900*256 f32

    // K1: logits = (inst + anch) @ wfc^T + bfc     (M=900, N=2496, K=256)
    {
        dim3 grid(KOUT / 64, (NANCH + 63) / 64);              // 39 x 15
        gemm_bias_f32<<<grid, 256, 0, stream>>>(inst, anch, wfc, bfc,
                                                logits, NANCH, KOUT, EMBED);
    }

    // K2: fused softmax + split sample + aggregate -> partial sums
    sample_agg_fused<<<dim3(NANCH * SPLIT), 256, 0, stream>>>(feat, kp, l2i, iwh,
                                                              logits, outpart);

    // K3: out = (sum_p outpart[p]) @ wproj^T + bproj   (M=900, N=256, K=256)
    {
        dim3 grid(EMBED / 64, (NANCH + 63) / 64);             // 4 x 15
        gemm_bias_sum4_f32<<<grid, 256, 0, stream>>>(outpart, wproj, bproj,
                                                     out, NANCH, EMBED, EMBED);
    }
}

// Round 14
// 231.678 us; speedup vs baseline: 1.0905x; 1.0103x over previous
//
#include <hip/hip_runtime.h>
#include <math.h>

#define EMBED   256
#define NCAM    6
#define NLVL    4
#define NPTS    13
#define NGRP    8
#define NANCH   900
#define NTERM   (NCAM*NLVL*NPTS)   /* 312 */
#define KOUT    (NTERM*NGRP)       /* 2496 */
#define TOTHW   14960
#define SPLIT   4
#define TPS     (NTERM/SPLIT)      /* 78 terms per split block */
#define WSTR    9                  /* LDS stride for [m][g] weights: odd => conflict-free */

// ---------------------------------------------------------------------------
// Tiled f32 GEMM:  C[m][n] = dot(A0[m]+A1[m], B[n]) + bias[n]
// BM=BN=64, BK=32, 256 threads, 4x4 accumulators; LDS padded to 68 floats/row
// so fragment reads are 16B-aligned ds_read_b128.
// ---------------------------------------------------------------------------
__global__ __launch_bounds__(256)
void gemm_bias_f32(const float* __restrict__ A0, const float* __restrict__ A1,
                   const float* __restrict__ B,  const float* __restrict__ bias,
                   float* __restrict__ Cout, int M, int N, int K)
{
    const int BK = 32;
    __shared__ alignas(16) float As[32][68];
    __shared__ alignas(16) float Bs[32][68];

    const int bm = blockIdx.y * 64;
    const int bn = blockIdx.x * 64;
    const int tid = threadIdx.x;
    const int tx = tid & 15;
    const int ty = tid >> 4;

    float acc[4][4] = {{0.f}};

    for (int k0 = 0; k0 < K; k0 += BK) {
        #pragma unroll
        for (int i = 0; i < 2; ++i) {
            int lin = (tid + i * 256) * 4;
            int r = lin >> 5;
            int cc = lin & 31;
            int gm = bm + r;
            float4 v = make_float4(0.f, 0.f, 0.f, 0.f);
            if (gm < M) {
                v = *reinterpret_cast<const float4*>(A0 + (size_t)gm * K + k0 + cc);
                if (A1) {
                    float4 v1 = *reinterpret_cast<const float4*>(A1 + (size_t)gm * K + k0 + cc);
                    v.x += v1.x; v.y += v1.y; v.z += v1.z; v.w += v1.w;
                }
            }
            As[cc + 0][r] = v.x; As[cc + 1][r] = v.y;
            As[cc + 2][r] = v.z; As[cc + 3][r] = v.w;

            int gn = bn + r;
            float4 w = make_float4(0.f, 0.f, 0.f, 0.f);
            if (gn < N) {
                w = *reinterpret_cast<const float4*>(B + (size_t)gn * K + k0 + cc);
            }
            Bs[cc + 0][r] = w.x; Bs[cc + 1][r] = w.y;
            Bs[cc + 2][r] = w.z; Bs[cc + 3][r] = w.w;
        }
        __syncthreads();

        #pragma unroll
        for (int k = 0; k < BK; ++k) {
            float4 a4 = *reinterpret_cast<const float4*>(&As[k][ty * 4]);
            float4 b4 = *reinterpret_cast<const float4*>(&Bs[k][tx * 4]);
            float a[4] = {a4.x, a4.y, a4.z, a4.w};
            float b[4] = {b4.x, b4.y, b4.z, b4.w};
            #pragma unroll
            for (int i = 0; i < 4; ++i)
                #pragma unroll
                for (int j = 0; j < 4; ++j)
                    acc[i][j] = fmaf(a[i], b[j], acc[i][j]);
        }
        __syncthreads();
    }

    #pragma unroll
    for (int i = 0; i < 4; ++i) {
        int m = bm + ty * 4 + i;
        if (m >= M) break;
        #pragma unroll
        for (int j = 0; j < 4; ++j) {
            int n = bn + tx * 4 + j;
            if (n < N) Cout[(size_t)m * N + n] = acc[i][j] + (bias ? bias[n] : 0.f);
        }
    }
}

// ---------------------------------------------------------------------------
// K3 variant: A = sum of 4 partial buffers (outpart[0..3]).
// ---------------------------------------------------------------------------
__global__ __launch_bounds__(256)
void gemm_bias_sum4_f32(const float* __restrict__ Ap,   // 4 x (M x K) stacked
                        const float* __restrict__ B, const float* __restrict__ bias,
                        float* __restrict__ Cout, int M, int N, int K)
{
    const int BK = 32;
    __shared__ alignas(16) float As[32][68];
    __shared__ alignas(16) float Bs[32][68];

    const int bm = blockIdx.y * 64;
    const int bn = blockIdx.x * 64;
    const int tid = threadIdx.x;
    const int tx = tid & 15;
    const int ty = tid >> 4;
    const size_t pstride = (size_t)M * K;

    float acc[4][4] = {{0.f}};

    for (int k0 = 0; k0 < K; k0 += BK) {
        #pragma unroll
        for (int i = 0; i < 2; ++i) {
            int lin = (tid + i * 256) * 4;
            int r = lin >> 5;
            int cc = lin & 31;
            int gm = bm + r;
            float4 v = make_float4(0.f, 0.f, 0.f, 0.f);
            if (gm < M) {
                const float* p = Ap + (size_t)gm * K + k0 + cc;
                float4 v0 = *reinterpret_cast<const float4*>(p);
                float4 v1 = *reinterpret_cast<const float4*>(p + pstride);
                float4 v2 = *reinterpret_cast<const float4*>(p + 2 * pstride);
                float4 v3 = *reinterpret_cast<const float4*>(p + 3 * pstride);
                v.x = v0.x + v1.x + v2.x + v3.x;
                v.y = v0.y + v1.y + v2.y + v3.y;
                v.z = v0.z + v1.z + v2.z + v3.z;
                v.w = v0.w + v1.w + v2.w + v3.w;
            }
            As[cc + 0][r] = v.x; As[cc + 1][r] = v.y;
            As[cc + 2][r] = v.z; As[cc + 3][r] = v.w;

            int gn = bn + r;
            float4 w = make_float4(0.f, 0.f, 0.f, 0.f);
            if (gn < N) {
                w = *reinterpret_cast<const float4*>(B + (size_t)gn * K + k0 + cc);
            }
            Bs[cc + 0][r] = w.x; Bs[cc + 1][r] = w.y;
            Bs[cc + 2][r] = w.z; Bs[cc + 3][r] = w.w;
        }
        __syncthreads();

        #pragma unroll
        for (int k = 0; k < BK; ++k) {
            float4 a4 = *reinterpret_cast<const float4*>(&As[k][ty * 4]);
            float4 b4 = *reinterpret_cast<const float4*>(&Bs[k][tx * 4]);
            float a[4] = {a4.x, a4.y, a4.z, a4.w};
            float b[4] = {b4.x, b4.y, b4.z, b4.w};
            #pragma unroll
            for (int i = 0; i < 4; ++i)
                #pragma unroll
                for (int j = 0; j < 4; ++j)
                    acc[i][j] = fmaf(a[i], b[j], acc[i][j]);
        }
        __syncthreads();
    }

    #pragma unroll
    for (int i = 0; i < 4; ++i) {
        int m = bm + ty * 4 + i;
        if (m >= M) break;
        #pragma unroll
        for (int j = 0; j < 4; ++j) {
            int n = bn + tx * 4 + j;
            if (n < N) Cout[(size_t)m * N + n] = acc[i][j] + (bias ? bias[n] : 0.f);
        }
    }
}

// ---------------------------------------------------------------------------
// Fused split kernel: block = (anchor, split). Loads the anchor's full 2496
// logits, softmaxes in LDS (stride-9: conflict-free), computes geometry for
// its 78 terms (compacted), then gathers wave-per-term with float4 lanes.
// ---------------------------------------------------------------------------
__global__ __launch_bounds__(256)
void sample_agg_fused(const float* __restrict__ feat,        // (NCAM, TOTHW, 256)
                      const float* __restrict__ key_points,  // (900, 13, 3)
                      const float* __restrict__ lidar2img,   // (6, 4, 4)
                      const float* __restrict__ image_wh,    // (6, 2)
                      const float* __restrict__ logits,      // (900, 2496)
                      float* __restrict__ outpart)           // (4, 900, 256)
{
    __shared__ float wl[NTERM * WSTR];             // 312*9 floats, softmaxed in place
    __shared__ alignas(16) int   cidx[TPS][4];     // *EMBED pre-multiplied
    __shared__ alignas(16) float cwgt[TPS][4];
    __shared__ int tmap[TPS];
    __shared__ int ncomp;
    __shared__ alignas(16) float red[4][EMBED];    // cross-wave reduction

    const int bid = blockIdx.x;
    const int a   = bid >> 2;          // / SPLIT
    const int sp  = bid & (SPLIT - 1);
    const int t0  = sp * TPS;
    const int tid = threadIdx.x;

    if (tid == 0) ncomp = 0;

    // ---- 1. load all logits for this anchor into stride-9 LDS ----
    {
        const float4* src = reinterpret_cast<const float4*>(logits + (size_t)a * KOUT);
        for (int i = tid; i < KOUT / 4; i += 256) {
            float4 v = src[i];
            int e = i * 4;                   // element = m*8+g
            float vv[4] = {v.x, v.y, v.z, v.w};
            #pragma unroll
            for (int q = 0; q < 4; ++q) {
                int m = (e + q) >> 3, g = (e + q) & 7;
                wl[m * WSTR + g] = vv[q];
            }
        }
    }
    __syncthreads();

    // ---- 2. softmax over m (312) per group g; 32 lanes per group ----
    {
        int g = tid >> 5;
        int j = tid & 31;
        float mx = -1e30f;
        for (int m = j; m < NTERM; m += 32) mx = fmaxf(mx, wl[m * WSTR + g]);
        #pragma unroll
        for (int s = 16; s > 0; s >>= 1) mx = fmaxf(mx, __shfl_xor(mx, s, 32));
        float sum = 0.f;
        for (int m = j; m < NTERM; m += 32) {
            float e = __expf(wl[m * WSTR + g] - mx);
            wl[m * WSTR + g] = e;
            sum += e;
        }
        #pragma unroll
        for (int s = 16; s > 0; s >>= 1) sum += __shfl_xor(sum, s, 32);
        float inv = 1.f / sum;
        for (int m = j; m < NTERM; m += 32) wl[m * WSTR + g] *= inv;
    }

    // ---- 3. geometry for this split's terms, compacted ----
    if (tid < TPS) {
        int t = t0 + tid;
        int cam = t / (NLVL * NPTS);
        int rem = t - cam * (NLVL * NPTS);
        int lvl = rem / NPTS;
        int p   = rem - lvl * NPTS;

        const float* kp = key_points + ((size_t)a * NPTS + p) * 3;
        float px = kp[0], py = kp[1], pz = kp[2];
        const float* M4 = lidar2img + cam * 16;
        float X = M4[0] * px + M4[1] * py + M4[2]  * pz + M4[3];
        float Y = M4[4] * px + M4[5] * py + M4[6]  * pz + M4[7];
        float Z = M4[8] * px + M4[9] * py + M4[10] * pz + M4[11];
        float zc = fmaxf(Z, 1e-5f);
        float u = (X / zc) / image_wh[cam * 2 + 0];
        float v = (Y / zc) / image_wh[cam * 2 + 1];

        int H = 64 >> lvl, W = 176 >> lvl;
        int st = (lvl == 0) ? 0 : (lvl == 1) ? 11264 : (lvl == 2) ? 14080 : 14784;

        float x = u * (float)W - 0.5f;
        float y = v * (float)H - 0.5f;
        float x0f = floorf(x), y0f = floorf(y);
        float wx1 = x - x0f, wy1 = y - y0f;
        float wx0 = 1.f - wx1, wy0 = 1.f - wy1;
        int x0 = (int)x0f, y0 = (int)y0f;
        int x1 = x0 + 1,   y1 = y0 + 1;

        bool vx0 = (x0 >= 0) & (x0 < W), vx1 = (x1 >= 0) & (x1 < W);
        bool vy0 = (y0 >= 0) & (y0 < H), vy1 = (y1 >= 0) & (y1 < H);
        int cx0 = min(max(x0, 0), W - 1), cx1 = min(max(x1, 0), W - 1);
        int cy0 = min(max(y0, 0), H - 1), cy1 = min(max(y1, 0), H - 1);

        float w00 = wx0 * wy0 * ((vx0 & vy0) ? 1.f : 0.f);
        float w10 = wx1 * wy0 * ((vx1 & vy0) ? 1.f : 0.f);
        float w01 = wx0 * wy1 * ((vx0 & vy1) ? 1.f : 0.f);
        float w11 = wx1 * wy1 * ((vx1 & vy1) ? 1.f : 0.f);

        if ((w00 != 0.f) | (w10 != 0.f) | (w01 != 0.f) | (w11 != 0.f)) {
            int slot = atomicAdd(&ncomp, 1);
            int base = cam * TOTHW + st;
            cidx[slot][0] = (base + cy0 * W + cx0) * EMBED;
            cidx[slot][1] = (base + cy0 * W + cx1) * EMBED;
            cidx[slot][2] = (base + cy1 * W + cx0) * EMBED;
            cidx[slot][3] = (base + cy1 * W + cx1) * EMBED;
            cwgt[slot][0] = w00;
            cwgt[slot][1] = w10;
            cwgt[slot][2] = w01;
            cwgt[slot][3] = w11;
            tmap[slot] = tid;               // local term index
        }
    }
    __syncthreads();

    // ---- 4. gather: wave-per-term, float4 per lane (1KB row per wave) ----
    const int wid  = tid >> 6;          // wave 0..3
    const int lane = tid & 63;
    const int c0   = lane * 4;          // channels c0..c0+3 (same group)
    const int g    = c0 >> 5;
    const int nt   = ncomp;

    float4 acc4 = make_float4(0.f, 0.f, 0.f, 0.f);
    const float* fb = feat + c0;

    for (int s = wid; s < nt; s += 4) {
        int4   I  = *reinterpret_cast<const int4*>(&cidx[s][0]);
        float4 Wt = *reinterpret_cast<const float4*>(&cwgt[s][0]);
        float  gw = wl[(t0 + tmap[s]) * WSTR + g];
        float4 v0 = *reinterpret_cast<const float4*>(fb + I.x);
        float4 v1 = *reinterpret_cast<const float4*>(fb + I.y);
        float4 v2 = *reinterpret_cast<const float4*>(fb + I.z);
        float4 v3 = *reinterpret_cast<const float4*>(fb + I.w);
        float sx = v0.x * Wt.x + v1.x * Wt.y + v2.x * Wt.z + v3.x * Wt.w;
        float sy = v0.y * Wt.x + v1.y * Wt.y + v2.y * Wt.z + v3.y * Wt.w;
        float sz = v0.z * Wt.x + v1.z * Wt.y + v2.z * Wt.z + v3.z * Wt.w;
        float sw = v0.w * Wt.x + v1.w * Wt.y + v2.w * Wt.z + v3.w * Wt.w;
        acc4.x = fmaf(sx, gw, acc4.x);
        acc4.y = fmaf(sy, gw, acc4.y);
        acc4.z = fmaf(sz, gw, acc4.z);
        acc4.w = fmaf(sw, gw, acc4.w);
    }
    *reinterpret_cast<float4*>(&red[wid][c0]) = acc4;
    __syncthreads();

    // ---- 5. cross-wave sum + store ----
    {
        const int c = tid;
        float r = red[0][c] + red[1][c] + red[2][c] + red[3][c];
        outpart[((size_t)sp * NANCH + a) * EMBED + c] = r;
    }
}

// ---------------------------------------------------------------------------
extern "C" void kernel_launch(void* const* d_in, const int* in_sizes, int n_in,
                              void* d_out, int out_size, void* d_ws, size_t ws_size,
                              hipStream_t stream)
{
    const float* feat   = (const float*)d_in[0];
    const float* kp     = (const float*)d_in[1];
    const float* l2i    = (const float*)d_in[2];
    const float* iwh    = (const float*)d_in[3];
    const float* inst   = (const float*)d_in[4];
    const float* anch   = (const float*)d_in[5];
    const float* wfc    = (const float*)d_in[6];
    const float* bfc    = (const float*)d_in[7];
    const float* wproj  = (const float*)d_in[8];
    const float* bproj  = (const float*)d_in[9];
    float* out = (float*)d_out;

    float* logits  = (float*)d_ws;                            // 900*2496 f32
    float* outpart = logits + (size_t)NANCH * KOUT;           // 4*900*256 f32

    // K1: logits = (inst + anch) @ wfc^T + bfc     (M=900, N=2496, K=256)
    {
        dim3 grid(KOUT / 64, (NANCH + 63) / 64);              // 39 x 15
        gemm_bias_f32<<<grid, 256, 0, stream>>>(inst, anch, wfc, bfc,
                                                logits, NANCH, KOUT, EMBED);
    }

    // K2: fused softmax + split sample + aggregate -> partial sums
    sample_agg_fused<<<dim3(NANCH * SPLIT), 256, 0, stream>>>(feat, kp, l2i, iwh,
                                                              logits, outpart);

    // K3: out = (sum_p outpart[p]) @ wproj^T + bproj   (M=900, N=256, K=256)
    {
        dim3 grid(EMBED / 64, (NANCH + 63) / 64);             // 4 x 15
        gemm_bias_sum4_f32<<<grid, 256, 0, stream>>>(outpart, wproj, bproj,
                                                     out, NANCH, EMBED, EMBED);
    }
}